// Round 10
// baseline (50.918 us; speedup 1.0000x reference)
//
#include <hip/hip_runtime.h>
#include <math.h>

#define NTOK 2048
#define HID  128
#define BB   4

typedef float f32x4 __attribute__((ext_vector_type(4)));

__device__ __forceinline__ double wave_red_d(double v) {
  #pragma unroll
  for (int o = 32; o; o >>= 1) v += __shfl_down(v, o, 64);
  return v;
}

// ---- Kernel A: blocks 0..31 = MLP (heads folded through W2);
// ----           blocks 32..35 = per-batch threshold via separable moments.
__global__ __launch_bounds__(256) void mlp_thr_kernel(
    const float* __restrict__ pc,
    const float* __restrict__ W1, const float* __restrict__ b1,
    const float* __restrict__ W2, const float* __restrict__ b2,
    const float* __restrict__ Wd, const float* __restrict__ bd,
    const float* __restrict__ Wr, const float* __restrict__ br,
    const float* __restrict__ Wm, const float* __restrict__ bm,
    float* __restrict__ outd, float* __restrict__ outr, float* __restrict__ outm,
    float* __restrict__ thr)
{
  const int tid = threadIdx.x;

  if (blockIdx.x >= 32) {
    const int wave = tid >> 6, lane = tid & 63;
    const int b = blockIdx.x - 32;
    const float2* r = (const float2*)(pc + (size_t)b * NTOK * 2);
    double m[10];
    #pragma unroll
    for (int j = 0; j < 10; ++j) m[j] = 0.0;
    for (int i = tid; i < NTOK; i += 256) {
      const float2 c = r[i];
      const double a = c.x, bq = c.y, u = 1.0 - (double)c.x, v = 1.0 - (double)c.y;
      const double a2 = a * a, b2v = bq * bq, u2 = u * u, v2 = v * v;
      m[0] += a2;       m[1] += b2v;
      m[2] += a2 * a2;  m[3] += b2v * b2v;  m[4] += a2 * b2v;
      m[5] += u2;       m[6] += v2;
      m[7] += u2 * u2;  m[8] += v2 * v2;    m[9] += u2 * v2;
    }
    #pragma unroll
    for (int j = 0; j < 10; ++j) m[j] = wave_red_d(m[j]);
    __shared__ double sm[4][10];
    if (lane == 0) {
      #pragma unroll
      for (int j = 0; j < 10; ++j) sm[wave][j] = m[j];
    }
    __syncthreads();
    if (tid == 0) {
      double t[10];
      #pragma unroll
      for (int j = 0; j < 10; ++j)
        t[j] = sm[0][j] + sm[1][j] + sm[2][j] + sm[3][j];
      const double Sq  = t[0] * t[5] + t[1] * t[6];
      const double Sqq = t[2] * t[7] + 2.0 * t[4] * t[9] + t[3] * t[8];
      const double M = (double)NTOK * (double)NTOK;
      const double mean = Sq / M;
      double var = (Sqq - Sq * Sq / M) / (M - 1.0);
      if (var < 0.0) var = 0.0;
      double sd = sqrt(var);
      if (sd < 1e-6) sd = 1e-6;
      thr[b] = (float)(mean + 1.25 * sd);
    }
    return;
  }

  // ---------------- MLP path --------------------------------------------
  __shared__ float fw[3][HID];
  __shared__ float fc[3];

  for (int idx = tid; idx < 3 * HID; idx += 256) {
    const int head = idx >> 7, k = idx & (HID - 1);
    const float* wh = (head == 0) ? Wd : (head == 1) ? Wr : Wm;
    const float4* w2row = (const float4*)(W2 + k * HID);
    const float4* wh4   = (const float4*)wh;
    float s = 0.f;
    #pragma unroll 4
    for (int j = 0; j < HID / 4; ++j) {
      const float4 a = w2row[j], w = wh4[j];
      s = fmaf(a.x, w.x, fmaf(a.y, w.y, fmaf(a.z, w.z, fmaf(a.w, w.w, s))));
    }
    fw[head][k] = s;
  }
  if (tid < 3) {
    const float* wh = (tid == 0) ? Wd : (tid == 1) ? Wr : Wm;
    const float bh  = (tid == 0) ? bd[0] : (tid == 1) ? br[0] : bm[0];
    const float4* b24 = (const float4*)b2;
    const float4* wh4 = (const float4*)wh;
    float s = 0.f;
    for (int j = 0; j < HID / 4; ++j) {
      const float4 a = b24[j], w = wh4[j];
      s = fmaf(a.x, w.x, fmaf(a.y, w.y, fmaf(a.z, w.z, fmaf(a.w, w.w, s))));
    }
    fc[tid] = s + bh;
  }
  __syncthreads();

  const int row = blockIdx.x * 256 + tid;
  const float2 c = ((const float2*)pc)[row];
  const float x0 = c.x, x1 = c.y;

  float dd = 0.f, rv = 0.f, mv = 0.f;
  #pragma unroll 4
  for (int k = 0; k < HID; ++k) {
    const float z = fmaf(x0, W1[k], fmaf(x1, W1[HID + k], b1[k]));
    const float h = z * __builtin_amdgcn_rcpf(1.f + __builtin_amdgcn_exp2f(-1.442695041f * z));
    dd = fmaf(h, fw[0][k], dd);
    rv = fmaf(h, fw[1][k], rv);
    mv = fmaf(h, fw[2][k], mv);
  }
  outd[row] = dd + fc[0];
  outr[row] = rv + fc[1];
  outm[row] = mv + fc[2];
}

// ---- Kernel B: row stats only (no attn stores). One row per wave, -------
// ---- butterfly reduce; lane 0 writes sc[b][s] (ws) and dfield[b][s]. ----
__global__ __launch_bounds__(256) void rowstats_kernel(
    const float* __restrict__ pc, const float* __restrict__ diffu,
    const float* __restrict__ thr,
    float* __restrict__ scbuf, float* __restrict__ dfield)
{
  const int b = blockIdx.y;
  const int wave = threadIdx.x >> 6, lane = threadIdx.x & 63;
  const int s = blockIdx.x * 4 + wave;           // one row per wave

  const float2* __restrict__ rr  = (const float2*)(pc + (size_t)b * NTOK * 2);
  const float4* __restrict__ rr4 = (const float4*)rr;
  const float4* __restrict__ sd4 = (const float4*)(diffu + b * NTOK);

  const float C = 1.2011224f;                    // sqrt(log2(e))
  float2 u[32];
  float  sdr[32];
  #pragma unroll
  for (int j = 0; j < 8; ++j) {
    const float4 c0 = rr4[lane * 2 + j * 128];
    const float4 c1 = rr4[lane * 2 + 1 + j * 128];
    u[j * 4 + 0] = make_float2(C * (1.f - c0.x), C * (1.f - c0.y));
    u[j * 4 + 1] = make_float2(C * (1.f - c0.z), C * (1.f - c0.w));
    u[j * 4 + 2] = make_float2(C * (1.f - c1.x), C * (1.f - c1.y));
    u[j * 4 + 3] = make_float2(C * (1.f - c1.z), C * (1.f - c1.w));
    const float4 dv = sd4[lane + j * 64];
    sdr[j * 4 + 0] = dv.x; sdr[j * 4 + 1] = dv.y;
    sdr[j * 4 + 2] = dv.z; sdr[j * 4 + 3] = dv.w;
  }

  const float Ts = thr[b] * 1.442695041f;        // scaled-domain threshold
  const float2 rc = rr[s];

  float rsum = 0.f, dot = 0.f;
  #pragma unroll
  for (int k = 0; k < 32; ++k) {
    const float d0 = rc.x * u[k].x;
    const float d1 = rc.y * u[k].y;
    const float q = fmaf(d0, d0, d1 * d1);       // = log2(e) * dist_sq
    float val = 0.f;
    if (q <= Ts)
      val = (q > 0.f)
          ? fmaf(d0 * rsqrtf(q), 0.5f, 0.5f) * __builtin_amdgcn_exp2f(-q)
          : 1.f;
    rsum += val;
    dot = fmaf(val, sdr[k], dot);
  }

  #pragma unroll
  for (int o = 1; o < 64; o <<= 1) {
    rsum += __shfl_xor(rsum, o, 64);
    dot  += __shfl_xor(dot, o, 64);
  }
  if (lane == 0) {
    const float sc = 1.f / (rsum + 1e-8f);
    scbuf[b * NTOK + s]  = sc;
    dfield[b * NTOK + s] = dot * sc;
  }
}

// ---- Kernel C: fill-shaped storer. Linear f32x4 index space, recompute ----
// ---- bias, scale by sc[s], plain stores. Inputs L1/L2-hot. ---------------
#define C_TOTAL (BB * NTOK * (NTOK / 4))         // 4,194,304 f32x4
#define C_STRIDE (2048 * 256)                    // grid*block
__global__ __launch_bounds__(256) void store_kernel(
    const float* __restrict__ pc, const float* __restrict__ thr,
    const float* __restrict__ scbuf, float* __restrict__ attn)
{
  const float C = 1.2011224f;
  const int tid0 = blockIdx.x * 256 + threadIdx.x;
  f32x4* __restrict__ out4 = (f32x4*)attn;

  #pragma unroll
  for (int it = 0; it < C_TOTAL / C_STRIDE; ++it) {
    const int idx = tid0 + it * C_STRIDE;        // flat f32x4 index
    const int b   = idx >> 20;                   // 2048*512 f32x4 per batch
    const int r   = idx & 1048575;
    const int s   = r >> 9;
    const int t4  = r & 511;

    const float2 rc = ((const float2*)pc)[(b << 11) + s];
    const float4 c0 = ((const float4*)pc)[(b << 10) + t4 * 2];
    const float4 c1 = ((const float4*)pc)[(b << 10) + t4 * 2 + 1];
    const float Ts  = thr[b] * 1.442695041f;
    const float scv = scbuf[(b << 11) + s];

    f32x4 o;
    #pragma unroll
    for (int j = 0; j < 4; ++j) {
      const float cx = (j == 0) ? c0.x : (j == 1) ? c0.z : (j == 2) ? c1.x : c1.z;
      const float cy = (j == 0) ? c0.y : (j == 1) ? c0.w : (j == 2) ? c1.y : c1.w;
      const float d0 = rc.x * fmaf(-C, cx, C);
      const float d1 = rc.y * fmaf(-C, cy, C);
      const float q  = fmaf(d0, d0, d1 * d1);
      float val = 0.f;
      if (q <= Ts)
        val = (q > 0.f)
            ? fmaf(d0 * rsqrtf(q), 0.5f, 0.5f) * __builtin_amdgcn_exp2f(-q)
            : 1.f;
      o[j] = val * scv;
    }
    out4[idx] = o;
  }
}

extern "C" void kernel_launch(void* const* d_in, const int* in_sizes, int n_in,
                              void* d_out, int out_size, void* d_ws, size_t ws_size,
                              hipStream_t stream) {
  const float* pc = (const float*)d_in[0];
  const float* W1 = (const float*)d_in[1];
  const float* b1 = (const float*)d_in[2];
  const float* W2 = (const float*)d_in[3];
  const float* b2 = (const float*)d_in[4];
  const float* Wd = (const float*)d_in[5];
  const float* bd = (const float*)d_in[6];
  const float* Wr = (const float*)d_in[7];
  const float* br = (const float*)d_in[8];
  const float* Wm = (const float*)d_in[9];
  const float* bm = (const float*)d_in[10];

  float* out    = (float*)d_out;
  float* outd   = out;                                // diffusion  [B*N]
  float* outr   = out + BB * NTOK;                    // reaction   [B*N]
  float* outm   = out + 2 * BB * NTOK;                // migration  [B*N]
  float* attn   = out + 3 * BB * NTOK;                // attn       [B*N*N]
  float* dfield = attn + (size_t)BB * NTOK * NTOK;    // diffusion_field [B*N]

  float* thr   = (float*)d_ws;                        // [BB]
  float* scbuf = thr + BB;                            // [BB*NTOK] row scales

  hipLaunchKernelGGL(mlp_thr_kernel, dim3(32 + BB), dim3(256), 0, stream,
                     pc, W1, b1, W2, b2, Wd, bd, Wr, br, Wm, bm,
                     outd, outr, outm, thr);
  hipLaunchKernelGGL(rowstats_kernel, dim3(NTOK / 4, BB), dim3(256), 0, stream,
                     pc, outd, thr, scbuf, dfield);
  hipLaunchKernelGGL(store_kernel, dim3(2048), dim3(256), 0, stream,
                     pc, thr, scbuf, attn);
}

// Round 11
// 37.867 us; speedup vs baseline: 1.3447x; 1.3447x over previous
//
#include <hip/hip_runtime.h>
#include <math.h>

#define NTOK 2048
#define HID  128
#define BB   4

typedef float f32x4 __attribute__((ext_vector_type(4)));

__device__ __forceinline__ double wave_red_d(double v) {
  #pragma unroll
  for (int o = 32; o; o >>= 1) v += __shfl_down(v, o, 64);
  return v;
}

// ---- Kernel A: blocks 0..31 = MLP (heads folded through W2);
// ----           blocks 32..35 = per-batch threshold via separable moments.
__global__ __launch_bounds__(256) void mlp_thr_kernel(
    const float* __restrict__ pc,
    const float* __restrict__ W1, const float* __restrict__ b1,
    const float* __restrict__ W2, const float* __restrict__ b2,
    const float* __restrict__ Wd, const float* __restrict__ bd,
    const float* __restrict__ Wr, const float* __restrict__ br,
    const float* __restrict__ Wm, const float* __restrict__ bm,
    float* __restrict__ outd, float* __restrict__ outr, float* __restrict__ outm,
    float* __restrict__ thr)
{
  const int tid = threadIdx.x;

  if (blockIdx.x >= 32) {
    const int wave = tid >> 6, lane = tid & 63;
    const int b = blockIdx.x - 32;
    const float2* r = (const float2*)(pc + (size_t)b * NTOK * 2);
    double m[10];
    #pragma unroll
    for (int j = 0; j < 10; ++j) m[j] = 0.0;
    for (int i = tid; i < NTOK; i += 256) {
      const float2 c = r[i];
      const double a = c.x, bq = c.y, u = 1.0 - (double)c.x, v = 1.0 - (double)c.y;
      const double a2 = a * a, b2v = bq * bq, u2 = u * u, v2 = v * v;
      m[0] += a2;       m[1] += b2v;
      m[2] += a2 * a2;  m[3] += b2v * b2v;  m[4] += a2 * b2v;
      m[5] += u2;       m[6] += v2;
      m[7] += u2 * u2;  m[8] += v2 * v2;    m[9] += u2 * v2;
    }
    #pragma unroll
    for (int j = 0; j < 10; ++j) m[j] = wave_red_d(m[j]);
    __shared__ double sm[4][10];
    if (lane == 0) {
      #pragma unroll
      for (int j = 0; j < 10; ++j) sm[wave][j] = m[j];
    }
    __syncthreads();
    if (tid == 0) {
      double t[10];
      #pragma unroll
      for (int j = 0; j < 10; ++j)
        t[j] = sm[0][j] + sm[1][j] + sm[2][j] + sm[3][j];
      const double Sq  = t[0] * t[5] + t[1] * t[6];
      const double Sqq = t[2] * t[7] + 2.0 * t[4] * t[9] + t[3] * t[8];
      const double M = (double)NTOK * (double)NTOK;
      const double mean = Sq / M;
      double var = (Sqq - Sq * Sq / M) / (M - 1.0);
      if (var < 0.0) var = 0.0;
      double sd = sqrt(var);
      if (sd < 1e-6) sd = 1e-6;
      thr[b] = (float)(mean + 1.25 * sd);
    }
    return;
  }

  // ---------------- MLP path --------------------------------------------
  __shared__ float fw[3][HID];
  __shared__ float fc[3];

  for (int idx = tid; idx < 3 * HID; idx += 256) {
    const int head = idx >> 7, k = idx & (HID - 1);
    const float* wh = (head == 0) ? Wd : (head == 1) ? Wr : Wm;
    const float4* w2row = (const float4*)(W2 + k * HID);
    const float4* wh4   = (const float4*)wh;
    float s = 0.f;
    #pragma unroll 4
    for (int j = 0; j < HID / 4; ++j) {
      const float4 a = w2row[j], w = wh4[j];
      s = fmaf(a.x, w.x, fmaf(a.y, w.y, fmaf(a.z, w.z, fmaf(a.w, w.w, s))));
    }
    fw[head][k] = s;
  }
  if (tid < 3) {
    const float* wh = (tid == 0) ? Wd : (tid == 1) ? Wr : Wm;
    const float bh  = (tid == 0) ? bd[0] : (tid == 1) ? br[0] : bm[0];
    const float4* b24 = (const float4*)b2;
    const float4* wh4 = (const float4*)wh;
    float s = 0.f;
    for (int j = 0; j < HID / 4; ++j) {
      const float4 a = b24[j], w = wh4[j];
      s = fmaf(a.x, w.x, fmaf(a.y, w.y, fmaf(a.z, w.z, fmaf(a.w, w.w, s))));
    }
    fc[tid] = s + bh;
  }
  __syncthreads();

  const int row = blockIdx.x * 256 + tid;
  const float2 c = ((const float2*)pc)[row];
  const float x0 = c.x, x1 = c.y;

  float dd = 0.f, rv = 0.f, mv = 0.f;
  #pragma unroll 4
  for (int k = 0; k < HID; ++k) {
    const float z = fmaf(x0, W1[k], fmaf(x1, W1[HID + k], b1[k]));
    const float h = z * __builtin_amdgcn_rcpf(1.f + __builtin_amdgcn_exp2f(-1.442695041f * z));
    dd = fmaf(h, fw[0][k], dd);
    rv = fmaf(h, fw[1][k], rv);
    mv = fmaf(h, fw[2][k], mv);
  }
  outd[row] = dd + fc[0];
  outr[row] = rv + fc[1];
  outm[row] = mv + fc[2];
}

// ---- Kernel B: attn, persistent wave-per-row, 2 rows/wave -----------------
// Grid (256, BB) = 1024 blocks = 4/CU (~12 waves/CU at ~150 VGPR).
// Wave stages its 32 columns' (1-r_t)*C and diffusion[t] once, then does
// rows s0 = blockIdx.x*4+wave and s0+1024. Zero barriers: butterfly reduce
// in-wave; row-1 compute overlaps row-0's in-flight stores (no vmcnt drain
// until endpgm). 4-way split accumulators cut the serial fma chain 32 -> 8.
__global__ __launch_bounds__(256) void attn_kernel(
    const float* __restrict__ pc, const float* __restrict__ diffu,
    const float* __restrict__ thr,
    float* __restrict__ attn, float* __restrict__ dfield)
{
  const int b = blockIdx.y;
  const int wave = threadIdx.x >> 6, lane = threadIdx.x & 63;

  const float2* __restrict__ rr  = (const float2*)(pc + (size_t)b * NTOK * 2);
  const float4* __restrict__ rr4 = (const float4*)rr;
  const float4* __restrict__ sd4 = (const float4*)(diffu + b * NTOK);

  const float C = 1.2011224f;                    // sqrt(log2(e))
  float2 u[32];
  float  sdr[32];
  #pragma unroll
  for (int j = 0; j < 8; ++j) {
    const float4 c0 = rr4[lane * 2 + j * 128];
    const float4 c1 = rr4[lane * 2 + 1 + j * 128];
    u[j * 4 + 0] = make_float2(C * (1.f - c0.x), C * (1.f - c0.y));
    u[j * 4 + 1] = make_float2(C * (1.f - c0.z), C * (1.f - c0.w));
    u[j * 4 + 2] = make_float2(C * (1.f - c1.x), C * (1.f - c1.y));
    u[j * 4 + 3] = make_float2(C * (1.f - c1.z), C * (1.f - c1.w));
    const float4 dv = sd4[lane + j * 64];
    sdr[j * 4 + 0] = dv.x; sdr[j * 4 + 1] = dv.y;
    sdr[j * 4 + 2] = dv.z; sdr[j * 4 + 3] = dv.w;
  }

  const float Ts = thr[b] * 1.442695041f;        // threshold, scaled domain
  float* __restrict__ dfb = dfield + b * NTOK;
  float* __restrict__ ab  = attn + (size_t)b * NTOK * NTOK;

  const int sbase = blockIdx.x * 4 + wave;       // rows sbase, sbase+1024

  #pragma unroll
  for (int half = 0; half < 2; ++half) {
    const int s = sbase + half * 1024;
    const float2 rc = rr[s];                     // wave-uniform
    float v[32];
    float rs[4] = {0.f, 0.f, 0.f, 0.f};
    float dt[4] = {0.f, 0.f, 0.f, 0.f};
    #pragma unroll
    for (int k = 0; k < 32; ++k) {
      const int j = k & 3;
      const float d0 = rc.x * u[k].x;
      const float d1 = rc.y * u[k].y;
      const float q = fmaf(d0, d0, d1 * d1);     // = log2(e) * dist_sq
      float val = 0.f;
      if (q <= Ts)
        val = (q > 0.f)
            ? fmaf(d0 * rsqrtf(q), 0.5f, 0.5f) * __builtin_amdgcn_exp2f(-q)
            : 1.f;
      v[k] = val;
      rs[j] += val;
      dt[j] = fmaf(val, sdr[k], dt[j]);
    }
    float rsum = (rs[0] + rs[1]) + (rs[2] + rs[3]);
    float dot  = (dt[0] + dt[1]) + (dt[2] + dt[3]);

    #pragma unroll
    for (int o = 1; o < 64; o <<= 1) {
      rsum += __shfl_xor(rsum, o, 64);
      dot  += __shfl_xor(dot, o, 64);
    }
    const float sc = 1.f / (rsum + 1e-8f);

    f32x4* arow4 = (f32x4*)(ab + (size_t)s * NTOK);
    #pragma unroll
    for (int j = 0; j < 8; ++j) {
      f32x4 o;
      o.x = v[j * 4 + 0] * sc; o.y = v[j * 4 + 1] * sc;
      o.z = v[j * 4 + 2] * sc; o.w = v[j * 4 + 3] * sc;
      __builtin_nontemporal_store(o, arow4 + lane + j * 64);
    }
    if (lane == 0) dfb[s] = dot * sc;
  }
}

extern "C" void kernel_launch(void* const* d_in, const int* in_sizes, int n_in,
                              void* d_out, int out_size, void* d_ws, size_t ws_size,
                              hipStream_t stream) {
  const float* pc = (const float*)d_in[0];
  const float* W1 = (const float*)d_in[1];
  const float* b1 = (const float*)d_in[2];
  const float* W2 = (const float*)d_in[3];
  const float* b2 = (const float*)d_in[4];
  const float* Wd = (const float*)d_in[5];
  const float* bd = (const float*)d_in[6];
  const float* Wr = (const float*)d_in[7];
  const float* br = (const float*)d_in[8];
  const float* Wm = (const float*)d_in[9];
  const float* bm = (const float*)d_in[10];

  float* out    = (float*)d_out;
  float* outd   = out;                                // diffusion  [B*N]
  float* outr   = out + BB * NTOK;                    // reaction   [B*N]
  float* outm   = out + 2 * BB * NTOK;                // migration  [B*N]
  float* attn   = out + 3 * BB * NTOK;                // attn       [B*N*N]
  float* dfield = attn + (size_t)BB * NTOK * NTOK;    // diffusion_field [B*N]

  float* thr = (float*)d_ws;                          // [BB]

  hipLaunchKernelGGL(mlp_thr_kernel, dim3(32 + BB), dim3(256), 0, stream,
                     pc, W1, b1, W2, b2, Wd, bd, Wr, br, Wm, bm,
                     outd, outr, outm, thr);
  hipLaunchKernelGGL(attn_kernel, dim3(256, BB), dim3(256), 0, stream,
                     pc, outd, thr, attn, dfield);
}